// Round 3
// baseline (301.636 us; speedup 1.0000x reference)
//
#include <hip/hip_runtime.h>
#include <stdint.h>

#define S_LEN 2048
#define DIM   1024
#define NH    16
#define HD    64
#define BATCH 4
#define M_ROWS (BATCH * S_LEN)  // 8192

typedef __attribute__((ext_vector_type(8))) __bf16 bf16x8;
typedef __attribute__((ext_vector_type(4))) float  f32x4;

union Frag { bf16x8 v; uint4 q; };

__device__ __forceinline__ ushort f2bf(float f) {
  union { float f; unsigned u; } x; x.f = f;
  unsigned r = x.u + 0x7fffu + ((x.u >> 16) & 1u);  // RNE
  return (ushort)(r >> 16);
}
// native cast (v_cvt_pk_bf16_f32 when paired)
__device__ __forceinline__ ushort f2bf_n(float f) {
  union { __bf16 b; ushort u; } x; x.b = (__bf16)f; return x.u;
}

__device__ __forceinline__ f32x4 mfma16(const Frag& a, const Frag& b, f32x4 c) {
  return __builtin_amdgcn_mfma_f32_16x16x32_bf16(a.v, b.v, c, 0, 0, 0);
}

// async global->LDS, 16B per lane; LDS dest = wave-uniform base + lane*16
__device__ __forceinline__ void gld_lds16(const ushort* g, ushort* l) {
  __builtin_amdgcn_global_load_lds(
      (__attribute__((address_space(1))) void*)g,
      (__attribute__((address_space(3))) void*)l, 16, 0, 0);
}

// ---------------- casts ----------------
__global__ void cast_x_kernel(const float* __restrict__ src, ushort* __restrict__ dst) {
  int i = blockIdx.x * 256 + threadIdx.x;
  float4 f = ((const float4*)src)[i];
  ushort4 u; u.x = f2bf(f.x); u.y = f2bf(f.y); u.z = f2bf(f.z); u.w = f2bf(f.w);
  ((ushort4*)dst)[i] = u;
}

__global__ void cast_w_kernel(const float* __restrict__ w0, const float* __restrict__ w1,
                              const float* __restrict__ w2, const float* __restrict__ w3,
                              ushort* __restrict__ d0, ushort* __restrict__ d1,
                              ushort* __restrict__ d2, ushort* __restrict__ d3) {
  const float* s; ushort* d;
  int z = blockIdx.y;
  if (z == 0) { s = w0; d = d0; } else if (z == 1) { s = w1; d = d1; }
  else if (z == 2) { s = w2; d = d2; } else { s = w3; d = d3; }
  int i = blockIdx.x * 256 + threadIdx.x;
  float4 f = ((const float4*)s)[i];
  ushort4 u; u.x = f2bf(f.x); u.y = f2bf(f.y); u.z = f2bf(f.z); u.w = f2bf(f.w);
  ((ushort4*)d)[i] = u;
}

// ---------------- 128x128 bt-GEMM, BK=64, XOR-swizzled LDS ----------------
// MODE 0: fused QKV.  grid (24,64): wsel=blockIdx.x>>3 picks Wq/Wk/Wv; writes
//         Q (scaled, [B,H,S,HD]) / K ([B,H,S,HD]) / V^T ([B,H,HD,S]).
// MODE 1: out-proj.   grid (8,64): f32 store out[m*DIM+e] + bias[e].
template <int MODE>
__global__ __launch_bounds__(256)
void gemm_bk64(const ushort* __restrict__ A,
               const ushort* __restrict__ B0, const ushort* __restrict__ B1,
               const ushort* __restrict__ B2,
               ushort* __restrict__ Qb, ushort* __restrict__ Kb, ushort* __restrict__ Vtb,
               float* __restrict__ outf, const float* __restrict__ bias, float scaleq) {
  __shared__ __align__(16) ushort As[128 * 64];
  __shared__ __align__(16) ushort Bs[128 * 64];
  const int K = DIM;
  int lane = threadIdx.x & 63, wave = threadIdx.x >> 6;
  int quad = lane >> 4, l15 = lane & 15;
  int rowBase = blockIdx.y * 128;
  int wsel, colBase;
  const ushort* Bt;
  if (MODE == 0) {
    wsel = blockIdx.x >> 3;
    colBase = (blockIdx.x & 7) * 128;
    Bt = (wsel == 0) ? B0 : (wsel == 1) ? B1 : B2;
  } else {
    wsel = 0;
    colBase = blockIdx.x * 128;
    Bt = B0;
  }
  int wm = (wave >> 1) * 64, wn = (wave & 1) * 64;

  const ushort* Ag = A + (size_t)rowBase * K;
  const ushort* Bg = Bt + (size_t)colBase * K;

  f32x4 acc[4][4];
#pragma unroll
  for (int i = 0; i < 4; i++)
#pragma unroll
    for (int j = 0; j < 4; j++) acc[i][j] = (f32x4){0.f, 0.f, 0.f, 0.f};

  for (int k0 = 0; k0 < K; k0 += 64) {
#pragma unroll
    for (int cc = 0; cc < 4; ++cc) {
      int c = wave * 4 + cc;                 // 16 chunks of 64 slots
      int s = c * 64 + lane;                 // 16B slot id in [0,1024)
      int row = s >> 3;
      int c8 = (s & 7) ^ (row & 7);          // swizzled chunk
      gld_lds16(Ag + (size_t)row * K + k0 + c8 * 8, &As[c * 512]);
      gld_lds16(Bg + (size_t)row * K + k0 + c8 * 8, &Bs[c * 512]);
    }
    __syncthreads();
    Frag af[4][2], bf[4][2];
#pragma unroll
    for (int t = 0; t < 4; t++) {
      int ar = wm + t * 16 + l15;
      int br = wn + t * 16 + l15;
#pragma unroll
      for (int kk = 0; kk < 2; kk++) {
        af[t][kk].q = *(const uint4*)&As[ar * 64 + (((kk * 4 + quad) ^ (ar & 7))) * 8];
        bf[t][kk].q = *(const uint4*)&Bs[br * 64 + (((kk * 4 + quad) ^ (br & 7))) * 8];
      }
    }
#pragma unroll
    for (int kk = 0; kk < 2; kk++)
#pragma unroll
      for (int i = 0; i < 4; i++)
#pragma unroll
        for (int j = 0; j < 4; j++) acc[i][j] = mfma16(af[i][kk], bf[j][kk], acc[i][j]);
    __syncthreads();
  }

#pragma unroll
  for (int i = 0; i < 4; i++) {
    int rowt = wm + i * 16 + quad * 4;
#pragma unroll
    for (int j = 0; j < 4; j++) {
      int e = colBase + wn + j * 16 + l15;  // within [0,1024)
      if (MODE == 0) {
        int h = e >> 6, hd = e & 63;
        if (wsel < 2) {
          ushort* dst = wsel ? Kb : Qb;
          float sc = wsel ? 1.f : scaleq;
#pragma unroll
          for (int r = 0; r < 4; r++) {
            int m = rowBase + rowt + r;
            int b = m >> 11, s = m & (S_LEN - 1);
            dst[((size_t)((b * NH + h) * S_LEN + s) << 6) + hd] = f2bf(acc[i][j][r] * sc);
          }
        } else {
          int m0 = rowBase + rowt;
          int b = m0 >> 11, s0 = m0 & (S_LEN - 1);
          ushort4 u;
          u.x = f2bf(acc[i][j][0]); u.y = f2bf(acc[i][j][1]);
          u.z = f2bf(acc[i][j][2]); u.w = f2bf(acc[i][j][3]);
          *(ushort4*)&Vtb[((size_t)((b * NH + h) * HD + hd) << 11) + s0] = u;
        }
      } else {
        float bv = bias[e];
#pragma unroll
        for (int r = 0; r < 4; r++) {
          int m = rowBase + rowt + r;
          outf[(size_t)m * DIM + e] = acc[i][j][r] + bv;
        }
      }
    }
  }
}

// ---------------- flash attention (causal; S^T orientation; no-max streaming softmax) ----------------
// v4 = v3 with the qt-map bug fixed (v3's map was non-bijective: tiles 8-11
// never computed -> correctness failure).
//  * P redistribution (S^T layout -> PV A-frags) IN REGISTERS via
//    v_permlane32_swap_b32 + v_permlane16_swap_b32 (lane algebra re-verified:
//    for target lane (quad,l15), pf[ks] word w = sw[2ks+(quad>>1)][w&1] from
//    quad' in {(0,1) for w<2->x-reg, (2,3)...}; the swap pair
//    x=[X0,X1,Y0,Y1]->[X0,X2,Y0,Y2], y=[X2,X3,Y2,Y3]->[X1,X3,Y1,Y3]
//    delivers words {x0,x1,y0,y1} for all 16 (quad,w) cells).
//  * l row-sum across quads also via permlane swaps (off the DS queue).
//  * single-buffered K/V: LDS = 32 KiB -> up to 5 blocks/CU;
//    __launch_bounds__(256,4) caps VGPR at 128 -> >=16 waves/CU.
//  * balanced + BIJECTIVE qt map: yq=y>>2, yr=y&3,
//    qt = {15-yr, 8+yr, 4+yr, 3-yr} -- union is exactly [0,15], and each
//    dispatch-residue class {j, j+4, j+8, j+12} sums to 30 (equal work per
//    round-robin CU group).
// grid (B*H, S/128).
__global__ __launch_bounds__(256, 4)
void flash_attn(const ushort* __restrict__ Qb, const ushort* __restrict__ Kb,
                const ushort* __restrict__ Vtb, ushort* __restrict__ Ctx) {
  __shared__ __align__(16) ushort Ks[128 * 64];   // K tile (also Q staging), swizzled
  __shared__ __align__(16) ushort Vs[64 * 128];   // V^T tile, swizzled

  int lane = threadIdx.x & 63, wave = threadIdx.x >> 6;
  int quad = lane >> 4, l15 = lane & 15;
  int bh = blockIdx.x;
  int yq = blockIdx.y >> 2, yr = blockIdx.y & 3;
  int qt = (yq == 0) ? (15 - yr) : (yq == 1) ? (8 + yr) : (yq == 2) ? (4 + yr) : (3 - yr);
  int q0 = qt * 128, wq0 = wave * 32;

  const ushort* Qh = Qb + (size_t)bh * S_LEN * HD;
  const ushort* Kh = Kb + (size_t)bh * S_LEN * HD;
  const ushort* Vh = Vtb + (size_t)bh * HD * S_LEN;

  // ---- stage Q tile (swizzled) into Ks, pull B-frags into registers
#pragma unroll
  for (int cc = 0; cc < 4; ++cc) {
    int c = wave * 4 + cc;
    int s = c * 64 + lane;
    int row = s >> 3;
    int c8 = (s & 7) ^ (row & 7);
    gld_lds16(Qh + (size_t)(q0 + row) * HD + c8 * 8, &Ks[c * 512]);
  }
  __syncthreads();
  Frag qf[2][2];  // B-frag: B[d][qrow]
#pragma unroll
  for (int it = 0; it < 2; ++it)
#pragma unroll
    for (int ks = 0; ks < 2; ++ks) {
      int row = wq0 + it * 16 + l15;
      int c8 = (ks * 4 + quad) ^ (row & 7);
      qf[it][ks].q = *(const uint4*)&Ks[row * 64 + c8 * 8];
    }
  __syncthreads();  // qf readers done before kt=0 staging overwrites Ks

  float lst[2] = {0.f, 0.f};
  f32x4 oacc[2][4];
#pragma unroll
  for (int it = 0; it < 2; ++it)
#pragma unroll
    for (int dt = 0; dt < 4; ++dt) oacc[it][dt] = (f32x4){0.f, 0.f, 0.f, 0.f};

  for (int kt = 0; kt <= qt; ++kt) {
    // ---- stage K (8 slots/row) and V^T (16 slots/row), both XOR-swizzled
#pragma unroll
    for (int cc = 0; cc < 4; ++cc) {
      int c = wave * 4 + cc;
      int s = c * 64 + lane;
      int krow = s >> 3, kc8 = (s & 7) ^ (krow & 7);
      int vrow = s >> 4, vc8 = (s & 15) ^ (vrow & 15);
      gld_lds16(Kh + (size_t)(kt * 128 + krow) * HD + kc8 * 8, &Ks[c * 512]);
      gld_lds16(Vh + (size_t)vrow * S_LEN + kt * 128 + vc8 * 8, &Vs[c * 512]);
    }
    __syncthreads();

    // ---- S^T = K · Q^T, fused mask+exp2+pack per jt
    // lane (quad,l15) computes P[k=16jt+4quad+r][q=wq0+16it+l15]; packed as
    // sw[it][jt][u] = bf16x2(p[2u], p[2u+1]).
    uint sw[2][8][2];
    float ps[2] = {0.f, 0.f};
    __builtin_amdgcn_s_setprio(1);
#pragma unroll
    for (int jt = 0; jt < 8; ++jt) {
      int row = jt * 16 + l15;
      Frag kf0, kf1;
      kf0.q = *(const uint4*)&Ks[row * 64 + ((quad ^ (row & 7))) * 8];
      kf1.q = *(const uint4*)&Ks[row * 64 + (((4 + quad) ^ (row & 7))) * 8];
#pragma unroll
      for (int it = 0; it < 2; ++it) {
        f32x4 a = (f32x4){0.f, 0.f, 0.f, 0.f};
        a = mfma16(kf0, qf[it][0], a);
        a = mfma16(kf1, qf[it][1], a);
        if (kt == qt) {  // causal mask, diagonal tile only
#pragma unroll
          for (int r = 0; r < 4; ++r)
            if (jt * 16 + quad * 4 + r > wq0 + it * 16 + l15) a[r] = -1e30f;
        }
        float p0 = exp2f(a[0]);
        float p1 = exp2f(a[1]);
        float p2 = exp2f(a[2]);
        float p3 = exp2f(a[3]);
        ps[it] += (p0 + p1) + (p2 + p3);
        union { ushort2 h; uint u; } w0, w1;
        w0.h.x = f2bf_n(p0); w0.h.y = f2bf_n(p1);
        w1.h.x = f2bf_n(p2); w1.h.y = f2bf_n(p3);
        sw[it][jt][0] = w0.u;
        sw[it][jt][1] = w1.u;
      }
    }
    __builtin_amdgcn_s_setprio(0);

    // ---- in-register P redistribution: quads exchange at fixed l15.
    // x=[X0 X1 X2 X3] (by quad), y=[Y0..Y3]; after 32-swap: x'=[X0 X1 Y0 Y1],
    // y'=[X2 X3 Y2 Y3]; after 16-swap: x''=[X0 X2 Y0 Y2] (A-frag word u),
    // y''=[X1 X3 Y1 Y3] (A-frag word 2+u).
    Frag pf[2][4];
#pragma unroll
    for (int it = 0; it < 2; ++it)
#pragma unroll
      for (int ks = 0; ks < 4; ++ks) {
        uint x0 = sw[it][2 * ks][0], y0 = sw[it][2 * ks + 1][0];
        uint x1 = sw[it][2 * ks][1], y1 = sw[it][2 * ks + 1][1];
        asm("v_permlane32_swap_b32 %0, %1" : "+v"(x0), "+v"(y0));
        asm("v_permlane16_swap_b32 %0, %1" : "+v"(x0), "+v"(y0));
        asm("v_permlane32_swap_b32 %0, %1" : "+v"(x1), "+v"(y1));
        asm("v_permlane16_swap_b32 %0, %1" : "+v"(x1), "+v"(y1));
        pf[it][ks].q = (uint4){x0, x1, y0, y1};
      }

    // ---- l row-sum across the 4 quads via permlane swaps (VALU, no DS)
#pragma unroll
    for (int it = 0; it < 2; ++it) {
      float a = ps[it], b = ps[it];
      asm("v_permlane32_swap_b32 %0, %1" : "+v"(a), "+v"(b));
      float s2 = a + b;           // lane + lane^32
      a = s2; b = s2;
      asm("v_permlane16_swap_b32 %0, %1" : "+v"(a), "+v"(b));
      lst[it] += a + b;           // full 4-quad row sum
    }

    // ---- O += P V (V frags shared across both q sub-tiles)
    __builtin_amdgcn_s_setprio(1);
#pragma unroll
    for (int dt = 0; dt < 4; ++dt) {
      int row = dt * 16 + l15;
      Frag vf[4];
#pragma unroll
      for (int ks = 0; ks < 4; ++ks)
        vf[ks].q = *(const uint4*)&Vs[row * 128 + (((ks * 4 + quad) ^ (row & 15))) * 8];
#pragma unroll
      for (int it = 0; it < 2; ++it) {
        f32x4 a = oacc[it][dt];
#pragma unroll
        for (int ks = 0; ks < 4; ++ks) a = mfma16(pf[it][ks], vf[ks], a);
        oacc[it][dt] = a;
      }
    }
    __builtin_amdgcn_s_setprio(0);

    __syncthreads();  // all waves done with Ks/Vs before restage
  }

  // ---- epilogue: normalize by l, store C-layout rows
  int b = bh >> 4, h = bh & 15;
#pragma unroll
  for (int it = 0; it < 2; ++it) {
    float linv = 1.f / lst[it];
    float lr[4];
#pragma unroll
    for (int r = 0; r < 4; ++r) lr[r] = __shfl(linv, quad * 4 + r);
#pragma unroll
    for (int r = 0; r < 4; ++r) {
      int qg = q0 + wq0 + it * 16 + quad * 4 + r;
      size_t base = ((size_t)(b * S_LEN + qg)) * DIM + h * HD;
#pragma unroll
      for (int dt = 0; dt < 4; ++dt)
        Ctx[base + dt * 16 + l15] = f2bf_n(oacc[it][dt][r] * lr[r]);
    }
  }
}

// ---------------- launch ----------------
extern "C" void kernel_launch(void* const* d_in, const int* in_sizes, int n_in,
                              void* d_out, int out_size, void* d_ws, size_t ws_size,
                              hipStream_t stream) {
  (void)in_sizes; (void)n_in; (void)out_size; (void)ws_size;
  const float* x  = (const float*)d_in[0];
  const float* Wq = (const float*)d_in[1];
  const float* Wk = (const float*)d_in[2];
  const float* Wv = (const float*)d_in[3];
  const float* Wo = (const float*)d_in[4];
  const float* bo = (const float*)d_in[5];
  float* out = (float*)d_out;

  ushort* Xb  = (ushort*)d_ws;                     // [8192][1024]
  ushort* Wqb = Xb  + (size_t)M_ROWS * DIM;
  ushort* Wkb = Wqb + (size_t)DIM * DIM;
  ushort* Wvb = Wkb + (size_t)DIM * DIM;
  ushort* Wob = Wvb + (size_t)DIM * DIM;
  ushort* Qb  = Wob + (size_t)DIM * DIM;           // [B,H,S,HD] (pre-scaled)
  ushort* Kb  = Qb  + (size_t)M_ROWS * DIM;        // [B,H,S,HD]
  ushort* Vtb = Kb  + (size_t)M_ROWS * DIM;        // [B,H,HD,S]
  ushort* Ctx = Vtb + (size_t)M_ROWS * DIM;        // [B,S,D]

  const float SCALE_Q = 0.18033688011112042f;  // log2(e) / sqrt(HD)

  cast_x_kernel<<<dim3(M_ROWS * DIM / 1024), 256, 0, stream>>>(x, Xb);
  cast_w_kernel<<<dim3(DIM * DIM / 1024, 4), 256, 0, stream>>>(Wq, Wk, Wv, Wo, Wqb, Wkb, Wvb, Wob);

  gemm_bk64<0><<<dim3(24, 64), 256, 0, stream>>>(Xb, Wqb, Wkb, Wvb, Qb, Kb, Vtb,
                                                 nullptr, nullptr, SCALE_Q);

  flash_attn<<<dim3(BATCH * NH, S_LEN / 128), 256, 0, stream>>>(Qb, Kb, Vtb, Ctx);

  gemm_bk64<1><<<dim3(8, 64), 256, 0, stream>>>(Ctx, Wob, nullptr, nullptr, nullptr, nullptr,
                                                nullptr, out, bo, 1.0f);
}

// Round 4
// 289.806 us; speedup vs baseline: 1.0408x; 1.0408x over previous
//
#include <hip/hip_runtime.h>
#include <stdint.h>

#define S_LEN 2048
#define DIM   1024
#define NH    16
#define HD    64
#define BATCH 4
#define M_ROWS (BATCH * S_LEN)  // 8192

typedef __attribute__((ext_vector_type(8))) __bf16 bf16x8;
typedef __attribute__((ext_vector_type(4))) float  f32x4;

union Frag { bf16x8 v; uint4 q; };

__device__ __forceinline__ ushort f2bf(float f) {
  union { float f; unsigned u; } x; x.f = f;
  unsigned r = x.u + 0x7fffu + ((x.u >> 16) & 1u);  // RNE
  return (ushort)(r >> 16);
}
// native cast (v_cvt_pk_bf16_f32 when paired)
__device__ __forceinline__ ushort f2bf_n(float f) {
  union { __bf16 b; ushort u; } x; x.b = (__bf16)f; return x.u;
}

__device__ __forceinline__ f32x4 mfma16(const Frag& a, const Frag& b, f32x4 c) {
  return __builtin_amdgcn_mfma_f32_16x16x32_bf16(a.v, b.v, c, 0, 0, 0);
}

// async global->LDS, 16B per lane; LDS dest = wave-uniform base + lane*16
__device__ __forceinline__ void gld_lds16(const ushort* g, ushort* l) {
  __builtin_amdgcn_global_load_lds(
      (__attribute__((address_space(1))) void*)g,
      (__attribute__((address_space(3))) void*)l, 16, 0, 0);
}

// ---------------- casts ----------------
__global__ void cast_x_kernel(const float* __restrict__ src, ushort* __restrict__ dst) {
  int i = blockIdx.x * 256 + threadIdx.x;
  float4 f = ((const float4*)src)[i];
  ushort4 u; u.x = f2bf(f.x); u.y = f2bf(f.y); u.z = f2bf(f.z); u.w = f2bf(f.w);
  ((ushort4*)dst)[i] = u;
}

__global__ void cast_w_kernel(const float* __restrict__ w0, const float* __restrict__ w1,
                              const float* __restrict__ w2, const float* __restrict__ w3,
                              ushort* __restrict__ d0, ushort* __restrict__ d1,
                              ushort* __restrict__ d2, ushort* __restrict__ d3) {
  const float* s; ushort* d;
  int z = blockIdx.y;
  if (z == 0) { s = w0; d = d0; } else if (z == 1) { s = w1; d = d1; }
  else if (z == 2) { s = w2; d = d2; } else { s = w3; d = d3; }
  int i = blockIdx.x * 256 + threadIdx.x;
  float4 f = ((const float4*)s)[i];
  ushort4 u; u.x = f2bf(f.x); u.y = f2bf(f.y); u.z = f2bf(f.z); u.w = f2bf(f.w);
  ((ushort4*)d)[i] = u;
}

// ---------------- 128x128 bt-GEMM, BK=64, XOR-swizzled LDS ----------------
// MODE 0: fused QKV.  grid (24,64): wsel=blockIdx.x>>3 picks Wq/Wk/Wv; writes
//         Q (scaled, [B,H,S,HD]) / K ([B,H,S,HD]) / V^T ([B,H,HD,S]).
// MODE 1: out-proj.   grid (8,64): f32 store out[m*DIM+e] + bias[e].
template <int MODE>
__global__ __launch_bounds__(256)
void gemm_bk64(const ushort* __restrict__ A,
               const ushort* __restrict__ B0, const ushort* __restrict__ B1,
               const ushort* __restrict__ B2,
               ushort* __restrict__ Qb, ushort* __restrict__ Kb, ushort* __restrict__ Vtb,
               float* __restrict__ outf, const float* __restrict__ bias, float scaleq) {
  __shared__ __align__(16) ushort As[128 * 64];
  __shared__ __align__(16) ushort Bs[128 * 64];
  const int K = DIM;
  int lane = threadIdx.x & 63, wave = threadIdx.x >> 6;
  int quad = lane >> 4, l15 = lane & 15;
  int rowBase = blockIdx.y * 128;
  int wsel, colBase;
  const ushort* Bt;
  if (MODE == 0) {
    wsel = blockIdx.x >> 3;
    colBase = (blockIdx.x & 7) * 128;
    Bt = (wsel == 0) ? B0 : (wsel == 1) ? B1 : B2;
  } else {
    wsel = 0;
    colBase = blockIdx.x * 128;
    Bt = B0;
  }
  int wm = (wave >> 1) * 64, wn = (wave & 1) * 64;

  const ushort* Ag = A + (size_t)rowBase * K;
  const ushort* Bg = Bt + (size_t)colBase * K;

  f32x4 acc[4][4];
#pragma unroll
  for (int i = 0; i < 4; i++)
#pragma unroll
    for (int j = 0; j < 4; j++) acc[i][j] = (f32x4){0.f, 0.f, 0.f, 0.f};

  for (int k0 = 0; k0 < K; k0 += 64) {
#pragma unroll
    for (int cc = 0; cc < 4; ++cc) {
      int c = wave * 4 + cc;                 // 16 chunks of 64 slots
      int s = c * 64 + lane;                 // 16B slot id in [0,1024)
      int row = s >> 3;
      int c8 = (s & 7) ^ (row & 7);          // swizzled chunk
      gld_lds16(Ag + (size_t)row * K + k0 + c8 * 8, &As[c * 512]);
      gld_lds16(Bg + (size_t)row * K + k0 + c8 * 8, &Bs[c * 512]);
    }
    __syncthreads();
    Frag af[4][2], bf[4][2];
#pragma unroll
    for (int t = 0; t < 4; t++) {
      int ar = wm + t * 16 + l15;
      int br = wn + t * 16 + l15;
#pragma unroll
      for (int kk = 0; kk < 2; kk++) {
        af[t][kk].q = *(const uint4*)&As[ar * 64 + (((kk * 4 + quad) ^ (ar & 7))) * 8];
        bf[t][kk].q = *(const uint4*)&Bs[br * 64 + (((kk * 4 + quad) ^ (br & 7))) * 8];
      }
    }
#pragma unroll
    for (int kk = 0; kk < 2; kk++)
#pragma unroll
      for (int i = 0; i < 4; i++)
#pragma unroll
        for (int j = 0; j < 4; j++) acc[i][j] = mfma16(af[i][kk], bf[j][kk], acc[i][j]);
    __syncthreads();
  }

#pragma unroll
  for (int i = 0; i < 4; i++) {
    int rowt = wm + i * 16 + quad * 4;
#pragma unroll
    for (int j = 0; j < 4; j++) {
      int e = colBase + wn + j * 16 + l15;  // within [0,1024)
      if (MODE == 0) {
        int h = e >> 6, hd = e & 63;
        if (wsel < 2) {
          ushort* dst = wsel ? Kb : Qb;
          float sc = wsel ? 1.f : scaleq;
#pragma unroll
          for (int r = 0; r < 4; r++) {
            int m = rowBase + rowt + r;
            int b = m >> 11, s = m & (S_LEN - 1);
            dst[((size_t)((b * NH + h) * S_LEN + s) << 6) + hd] = f2bf(acc[i][j][r] * sc);
          }
        } else {
          int m0 = rowBase + rowt;
          int b = m0 >> 11, s0 = m0 & (S_LEN - 1);
          ushort4 u;
          u.x = f2bf(acc[i][j][0]); u.y = f2bf(acc[i][j][1]);
          u.z = f2bf(acc[i][j][2]); u.w = f2bf(acc[i][j][3]);
          *(ushort4*)&Vtb[((size_t)((b * NH + h) * HD + hd) << 11) + s0] = u;
        }
      } else {
        float bv = bias[e];
#pragma unroll
        for (int r = 0; r < 4; r++) {
          int m = rowBase + rowt + r;
          outf[(size_t)m * DIM + e] = acc[i][j][r] + bv;
        }
      }
    }
  }
}

// ---------------- flash attention (causal; S^T orientation; no-max streaming softmax) ----------------
// v5 = v4 with __launch_bounds__(256) (no waves-per-EU arg).
// R3 evidence: the ",4" hint made the allocator target a 64-VGPR budget ->
// massive scratch spills (WRITE_SIZE 16.4->42.0 MB, FETCH +6 MB) that swamped
// the occupancy gain (18->30%). Live-set is ~110 VGPR; plain bounds allocates
// ~100-130 (R0/R1 evidence) with zero spills while still permitting 16
// waves/CU.
//  * P redistribution (S^T -> PV A-frags) in registers via
//    v_permlane32_swap_b32 + v_permlane16_swap_b32 (verified lane algebra;
//    R3 passed with absmax identical to the LDS path).
//  * l row-sum across quads via permlane swaps (off the DS queue).
//  * single-buffered K/V: LDS = 32 KiB; bank conflicts measured 0 (R3).
//  * balanced + bijective qt map {15-yr, 8+yr, 4+yr, 3-yr}.
// grid (B*H, S/128).
__global__ __launch_bounds__(256)
void flash_attn(const ushort* __restrict__ Qb, const ushort* __restrict__ Kb,
                const ushort* __restrict__ Vtb, ushort* __restrict__ Ctx) {
  __shared__ __align__(16) ushort Ks[128 * 64];   // K tile (also Q staging), swizzled
  __shared__ __align__(16) ushort Vs[64 * 128];   // V^T tile, swizzled

  int lane = threadIdx.x & 63, wave = threadIdx.x >> 6;
  int quad = lane >> 4, l15 = lane & 15;
  int bh = blockIdx.x;
  int yq = blockIdx.y >> 2, yr = blockIdx.y & 3;
  int qt = (yq == 0) ? (15 - yr) : (yq == 1) ? (8 + yr) : (yq == 2) ? (4 + yr) : (3 - yr);
  int q0 = qt * 128, wq0 = wave * 32;

  const ushort* Qh = Qb + (size_t)bh * S_LEN * HD;
  const ushort* Kh = Kb + (size_t)bh * S_LEN * HD;
  const ushort* Vh = Vtb + (size_t)bh * HD * S_LEN;

  // ---- stage Q tile (swizzled) into Ks, pull B-frags into registers
#pragma unroll
  for (int cc = 0; cc < 4; ++cc) {
    int c = wave * 4 + cc;
    int s = c * 64 + lane;
    int row = s >> 3;
    int c8 = (s & 7) ^ (row & 7);
    gld_lds16(Qh + (size_t)(q0 + row) * HD + c8 * 8, &Ks[c * 512]);
  }
  __syncthreads();
  Frag qf[2][2];  // B-frag: B[d][qrow]
#pragma unroll
  for (int it = 0; it < 2; ++it)
#pragma unroll
    for (int ks = 0; ks < 2; ++ks) {
      int row = wq0 + it * 16 + l15;
      int c8 = (ks * 4 + quad) ^ (row & 7);
      qf[it][ks].q = *(const uint4*)&Ks[row * 64 + c8 * 8];
    }
  __syncthreads();  // qf readers done before kt=0 staging overwrites Ks

  float lst[2] = {0.f, 0.f};
  f32x4 oacc[2][4];
#pragma unroll
  for (int it = 0; it < 2; ++it)
#pragma unroll
    for (int dt = 0; dt < 4; ++dt) oacc[it][dt] = (f32x4){0.f, 0.f, 0.f, 0.f};

  for (int kt = 0; kt <= qt; ++kt) {
    // ---- stage K (8 slots/row) and V^T (16 slots/row), both XOR-swizzled
#pragma unroll
    for (int cc = 0; cc < 4; ++cc) {
      int c = wave * 4 + cc;
      int s = c * 64 + lane;
      int krow = s >> 3, kc8 = (s & 7) ^ (krow & 7);
      int vrow = s >> 4, vc8 = (s & 15) ^ (vrow & 15);
      gld_lds16(Kh + (size_t)(kt * 128 + krow) * HD + kc8 * 8, &Ks[c * 512]);
      gld_lds16(Vh + (size_t)vrow * S_LEN + kt * 128 + vc8 * 8, &Vs[c * 512]);
    }
    __syncthreads();

    // ---- S^T = K · Q^T, fused mask+exp2+pack per jt
    // lane (quad,l15) computes P[k=16jt+4quad+r][q=wq0+16it+l15]; packed as
    // sw[it][jt][u] = bf16x2(p[2u], p[2u+1]).
    uint sw[2][8][2];
    float ps[2] = {0.f, 0.f};
    __builtin_amdgcn_s_setprio(1);
#pragma unroll
    for (int jt = 0; jt < 8; ++jt) {
      int row = jt * 16 + l15;
      Frag kf0, kf1;
      kf0.q = *(const uint4*)&Ks[row * 64 + ((quad ^ (row & 7))) * 8];
      kf1.q = *(const uint4*)&Ks[row * 64 + (((4 + quad) ^ (row & 7))) * 8];
#pragma unroll
      for (int it = 0; it < 2; ++it) {
        f32x4 a = (f32x4){0.f, 0.f, 0.f, 0.f};
        a = mfma16(kf0, qf[it][0], a);
        a = mfma16(kf1, qf[it][1], a);
        if (kt == qt) {  // causal mask, diagonal tile only
#pragma unroll
          for (int r = 0; r < 4; ++r)
            if (jt * 16 + quad * 4 + r > wq0 + it * 16 + l15) a[r] = -1e30f;
        }
        float p0 = exp2f(a[0]);
        float p1 = exp2f(a[1]);
        float p2 = exp2f(a[2]);
        float p3 = exp2f(a[3]);
        ps[it] += (p0 + p1) + (p2 + p3);
        union { ushort2 h; uint u; } w0, w1;
        w0.h.x = f2bf_n(p0); w0.h.y = f2bf_n(p1);
        w1.h.x = f2bf_n(p2); w1.h.y = f2bf_n(p3);
        sw[it][jt][0] = w0.u;
        sw[it][jt][1] = w1.u;
      }
    }
    __builtin_amdgcn_s_setprio(0);

    // ---- in-register P redistribution: quads exchange at fixed l15.
    // x=[X0 X1 X2 X3] (by quad), y=[Y0..Y3]; after 32-swap: x'=[X0 X1 Y0 Y1],
    // y'=[X2 X3 Y2 Y3]; after 16-swap: x''=[X0 X2 Y0 Y2] (A-frag word u),
    // y''=[X1 X3 Y1 Y3] (A-frag word 2+u).
    Frag pf[2][4];
#pragma unroll
    for (int it = 0; it < 2; ++it)
#pragma unroll
      for (int ks = 0; ks < 4; ++ks) {
        uint x0 = sw[it][2 * ks][0], y0 = sw[it][2 * ks + 1][0];
        uint x1 = sw[it][2 * ks][1], y1 = sw[it][2 * ks + 1][1];
        asm("v_permlane32_swap_b32 %0, %1" : "+v"(x0), "+v"(y0));
        asm("v_permlane16_swap_b32 %0, %1" : "+v"(x0), "+v"(y0));
        asm("v_permlane32_swap_b32 %0, %1" : "+v"(x1), "+v"(y1));
        asm("v_permlane16_swap_b32 %0, %1" : "+v"(x1), "+v"(y1));
        pf[it][ks].q = (uint4){x0, x1, y0, y1};
      }

    // ---- l row-sum across the 4 quads via permlane swaps (VALU, no DS)
#pragma unroll
    for (int it = 0; it < 2; ++it) {
      float a = ps[it], b = ps[it];
      asm("v_permlane32_swap_b32 %0, %1" : "+v"(a), "+v"(b));
      float s2 = a + b;           // lane + lane^32
      a = s2; b = s2;
      asm("v_permlane16_swap_b32 %0, %1" : "+v"(a), "+v"(b));
      lst[it] += a + b;           // full 4-quad row sum
    }

    // ---- O += P V (V frags shared across both q sub-tiles)
    __builtin_amdgcn_s_setprio(1);
#pragma unroll
    for (int dt = 0; dt < 4; ++dt) {
      int row = dt * 16 + l15;
      Frag vf[4];
#pragma unroll
      for (int ks = 0; ks < 4; ++ks)
        vf[ks].q = *(const uint4*)&Vs[row * 128 + (((ks * 4 + quad) ^ (row & 15))) * 8];
#pragma unroll
      for (int it = 0; it < 2; ++it) {
        f32x4 a = oacc[it][dt];
#pragma unroll
        for (int ks = 0; ks < 4; ++ks) a = mfma16(pf[it][ks], vf[ks], a);
        oacc[it][dt] = a;
      }
    }
    __builtin_amdgcn_s_setprio(0);

    __syncthreads();  // all waves done with Ks/Vs before restage
  }

  // ---- epilogue: normalize by l, store C-layout rows
  int b = bh >> 4, h = bh & 15;
#pragma unroll
  for (int it = 0; it < 2; ++it) {
    float linv = 1.f / lst[it];
    float lr[4];
#pragma unroll
    for (int r = 0; r < 4; ++r) lr[r] = __shfl(linv, quad * 4 + r);
#pragma unroll
    for (int r = 0; r < 4; ++r) {
      int qg = q0 + wq0 + it * 16 + quad * 4 + r;
      size_t base = ((size_t)(b * S_LEN + qg)) * DIM + h * HD;
#pragma unroll
      for (int dt = 0; dt < 4; ++dt)
        Ctx[base + dt * 16 + l15] = f2bf_n(oacc[it][dt][r] * lr[r]);
    }
  }
}

// ---------------- launch ----------------
extern "C" void kernel_launch(void* const* d_in, const int* in_sizes, int n_in,
                              void* d_out, int out_size, void* d_ws, size_t ws_size,
                              hipStream_t stream) {
  (void)in_sizes; (void)n_in; (void)out_size; (void)ws_size;
  const float* x  = (const float*)d_in[0];
  const float* Wq = (const float*)d_in[1];
  const float* Wk = (const float*)d_in[2];
  const float* Wv = (const float*)d_in[3];
  const float* Wo = (const float*)d_in[4];
  const float* bo = (const float*)d_in[5];
  float* out = (float*)d_out;

  ushort* Xb  = (ushort*)d_ws;                     // [8192][1024]
  ushort* Wqb = Xb  + (size_t)M_ROWS * DIM;
  ushort* Wkb = Wqb + (size_t)DIM * DIM;
  ushort* Wvb = Wkb + (size_t)DIM * DIM;
  ushort* Wob = Wvb + (size_t)DIM * DIM;
  ushort* Qb  = Wob + (size_t)DIM * DIM;           // [B,H,S,HD] (pre-scaled)
  ushort* Kb  = Qb  + (size_t)M_ROWS * DIM;        // [B,H,S,HD]
  ushort* Vtb = Kb  + (size_t)M_ROWS * DIM;        // [B,H,HD,S]
  ushort* Ctx = Vtb + (size_t)M_ROWS * DIM;        // [B,S,D]

  const float SCALE_Q = 0.18033688011112042f;  // log2(e) / sqrt(HD)

  cast_x_kernel<<<dim3(M_ROWS * DIM / 1024), 256, 0, stream>>>(x, Xb);
  cast_w_kernel<<<dim3(DIM * DIM / 1024, 4), 256, 0, stream>>>(Wq, Wk, Wv, Wo, Wqb, Wkb, Wvb, Wob);

  gemm_bk64<0><<<dim3(24, 64), 256, 0, stream>>>(Xb, Wqb, Wkb, Wvb, Qb, Kb, Vtb,
                                                 nullptr, nullptr, SCALE_Q);

  flash_attn<<<dim3(BATCH * NH, S_LEN / 128), 256, 0, stream>>>(Qb, Kb, Vtb, Ctx);

  gemm_bk64<1><<<dim3(8, 64), 256, 0, stream>>>(Ctx, Wob, nullptr, nullptr, nullptr, nullptr,
                                                nullptr, out, bo, 1.0f);
}

// Round 5
// 263.313 us; speedup vs baseline: 1.1455x; 1.1006x over previous
//
#include <hip/hip_runtime.h>
#include <stdint.h>

#define S_LEN 2048
#define DIM   1024
#define NH    16
#define HD    64
#define BATCH 4
#define M_ROWS (BATCH * S_LEN)  // 8192

typedef __attribute__((ext_vector_type(8))) __bf16 bf16x8;
typedef __attribute__((ext_vector_type(4))) float  f32x4;

union Frag { bf16x8 v; uint4 q; };

__device__ __forceinline__ ushort f2bf(float f) {
  union { float f; unsigned u; } x; x.f = f;
  unsigned r = x.u + 0x7fffu + ((x.u >> 16) & 1u);  // RNE
  return (ushort)(r >> 16);
}
// native cast (v_cvt_pk_bf16_f32 when paired)
__device__ __forceinline__ ushort f2bf_n(float f) {
  union { __bf16 b; ushort u; } x; x.b = (__bf16)f; return x.u;
}

__device__ __forceinline__ f32x4 mfma16(const Frag& a, const Frag& b, f32x4 c) {
  return __builtin_amdgcn_mfma_f32_16x16x32_bf16(a.v, b.v, c, 0, 0, 0);
}

// async global->LDS, 16B per lane; LDS dest = wave-uniform base + lane*16
__device__ __forceinline__ void gld_lds16(const ushort* g, ushort* l) {
  __builtin_amdgcn_global_load_lds(
      (__attribute__((address_space(1))) void*)g,
      (__attribute__((address_space(3))) void*)l, 16, 0, 0);
}

// ---------------- casts ----------------
__global__ void cast_x_kernel(const float* __restrict__ src, ushort* __restrict__ dst) {
  int i = blockIdx.x * 256 + threadIdx.x;
  float4 f = ((const float4*)src)[i];
  ushort4 u; u.x = f2bf(f.x); u.y = f2bf(f.y); u.z = f2bf(f.z); u.w = f2bf(f.w);
  ((ushort4*)dst)[i] = u;
}

__global__ void cast_w_kernel(const float* __restrict__ w0, const float* __restrict__ w1,
                              const float* __restrict__ w2, const float* __restrict__ w3,
                              ushort* __restrict__ d0, ushort* __restrict__ d1,
                              ushort* __restrict__ d2, ushort* __restrict__ d3) {
  const float* s; ushort* d;
  int z = blockIdx.y;
  if (z == 0) { s = w0; d = d0; } else if (z == 1) { s = w1; d = d1; }
  else if (z == 2) { s = w2; d = d2; } else { s = w3; d = d3; }
  int i = blockIdx.x * 256 + threadIdx.x;
  float4 f = ((const float4*)s)[i];
  ushort4 u; u.x = f2bf(f.x); u.y = f2bf(f.y); u.z = f2bf(f.z); u.w = f2bf(f.w);
  ((ushort4*)d)[i] = u;
}

// ---------------- 128x128 bt-GEMM, BK=64, XOR-swizzled LDS ----------------
// MODE 0: fused QKV.  grid (24,64): wsel=blockIdx.x>>3 picks Wq/Wk/Wv; writes
//         Q (scaled, [B,H,S,HD]) / K ([B,H,S,HD]) / V^T ([B,H,HD,S]).
// MODE 1: out-proj.   grid (8,64): f32 store out[m*DIM+e] + bias[e].
template <int MODE>
__global__ __launch_bounds__(256)
void gemm_bk64(const ushort* __restrict__ A,
               const ushort* __restrict__ B0, const ushort* __restrict__ B1,
               const ushort* __restrict__ B2,
               ushort* __restrict__ Qb, ushort* __restrict__ Kb, ushort* __restrict__ Vtb,
               float* __restrict__ outf, const float* __restrict__ bias, float scaleq) {
  __shared__ __align__(16) ushort As[128 * 64];
  __shared__ __align__(16) ushort Bs[128 * 64];
  const int K = DIM;
  int lane = threadIdx.x & 63, wave = threadIdx.x >> 6;
  int quad = lane >> 4, l15 = lane & 15;
  int rowBase = blockIdx.y * 128;
  int wsel, colBase;
  const ushort* Bt;
  if (MODE == 0) {
    wsel = blockIdx.x >> 3;
    colBase = (blockIdx.x & 7) * 128;
    Bt = (wsel == 0) ? B0 : (wsel == 1) ? B1 : B2;
  } else {
    wsel = 0;
    colBase = blockIdx.x * 128;
    Bt = B0;
  }
  int wm = (wave >> 1) * 64, wn = (wave & 1) * 64;

  const ushort* Ag = A + (size_t)rowBase * K;
  const ushort* Bg = Bt + (size_t)colBase * K;

  f32x4 acc[4][4];
#pragma unroll
  for (int i = 0; i < 4; i++)
#pragma unroll
    for (int j = 0; j < 4; j++) acc[i][j] = (f32x4){0.f, 0.f, 0.f, 0.f};

  for (int k0 = 0; k0 < K; k0 += 64) {
#pragma unroll
    for (int cc = 0; cc < 4; ++cc) {
      int c = wave * 4 + cc;                 // 16 chunks of 64 slots
      int s = c * 64 + lane;                 // 16B slot id in [0,1024)
      int row = s >> 3;
      int c8 = (s & 7) ^ (row & 7);          // swizzled chunk
      gld_lds16(Ag + (size_t)row * K + k0 + c8 * 8, &As[c * 512]);
      gld_lds16(Bg + (size_t)row * K + k0 + c8 * 8, &Bs[c * 512]);
    }
    __syncthreads();
    Frag af[4][2], bf[4][2];
#pragma unroll
    for (int t = 0; t < 4; t++) {
      int ar = wm + t * 16 + l15;
      int br = wn + t * 16 + l15;
#pragma unroll
      for (int kk = 0; kk < 2; kk++) {
        af[t][kk].q = *(const uint4*)&As[ar * 64 + (((kk * 4 + quad) ^ (ar & 7))) * 8];
        bf[t][kk].q = *(const uint4*)&Bs[br * 64 + (((kk * 4 + quad) ^ (br & 7))) * 8];
      }
    }
#pragma unroll
    for (int kk = 0; kk < 2; kk++)
#pragma unroll
      for (int i = 0; i < 4; i++)
#pragma unroll
        for (int j = 0; j < 4; j++) acc[i][j] = mfma16(af[i][kk], bf[j][kk], acc[i][j]);
    __syncthreads();
  }

#pragma unroll
  for (int i = 0; i < 4; i++) {
    int rowt = wm + i * 16 + quad * 4;
#pragma unroll
    for (int j = 0; j < 4; j++) {
      int e = colBase + wn + j * 16 + l15;  // within [0,1024)
      if (MODE == 0) {
        int h = e >> 6, hd = e & 63;
        if (wsel < 2) {
          ushort* dst = wsel ? Kb : Qb;
          float sc = wsel ? 1.f : scaleq;
#pragma unroll
          for (int r = 0; r < 4; r++) {
            int m = rowBase + rowt + r;
            int b = m >> 11, s = m & (S_LEN - 1);
            dst[((size_t)((b * NH + h) * S_LEN + s) << 6) + hd] = f2bf(acc[i][j][r] * sc);
          }
        } else {
          int m0 = rowBase + rowt;
          int b = m0 >> 11, s0 = m0 & (S_LEN - 1);
          ushort4 u;
          u.x = f2bf(acc[i][j][0]); u.y = f2bf(acc[i][j][1]);
          u.z = f2bf(acc[i][j][2]); u.w = f2bf(acc[i][j][3]);
          *(ushort4*)&Vtb[((size_t)((b * NH + h) * HD + hd) << 11) + s0] = u;
        }
      } else {
        float bv = bias[e];
#pragma unroll
        for (int r = 0; r < 4; r++) {
          int m = rowBase + rowt + r;
          outf[(size_t)m * DIM + e] = acc[i][j][r] + bv;
        }
      }
    }
  }
}

// ---------------- flash attention (causal; S^T orientation; no-max streaming softmax) ----------------
// v6: R4 post-mortem showed the v4 regression was the exp2 fusion INSIDE the
// jt MFMA loop (MFMA->transcendental serial dependency per jt; MfmaUtil 17->12,
// VALU busy-time +37%). v6 de-fuses back to R0's structure (pure 16-MFMA burst,
// then mask, then exp2/pack burst) while keeping v4's wins:
//  * permlane P-redistribution (no DS P round-trip; bank conflicts measured 0)
//  * 32 KiB single-buffered LDS, plain __launch_bounds__(256) (no spills)
//  * bijective balanced qt map {15-yr, 8+yr, 4+yr, 3-yr}
// NEW: softmax denominator via MFMA ones-trick -- lacc[it] += pf[it][ks] x ONES
// gives D[q][j] = sum_k P[k][q] for every j, so lacc[it][r] = l[q] (uniform in
// l15). Deletes 64 v_add_f32 + 8-op permlane reduction per iter (~25% of the
// per-iter VALU) and the epilogue shfl; costs 8 MFMAs on a 12%-utilized pipe.
// l now derives from the SAME bf16 P as O -> numerator/denominator errors
// correlate (absmax expected unchanged).
// grid (B*H, S/128).
__global__ __launch_bounds__(256)
void flash_attn(const ushort* __restrict__ Qb, const ushort* __restrict__ Kb,
                const ushort* __restrict__ Vtb, ushort* __restrict__ Ctx) {
  __shared__ __align__(16) ushort Ks[128 * 64];   // K tile (also Q staging), swizzled
  __shared__ __align__(16) ushort Vs[64 * 128];   // V^T tile, swizzled

  int lane = threadIdx.x & 63, wave = threadIdx.x >> 6;
  int quad = lane >> 4, l15 = lane & 15;
  int bh = blockIdx.x;
  int yq = blockIdx.y >> 2, yr = blockIdx.y & 3;
  int qt = (yq == 0) ? (15 - yr) : (yq == 1) ? (8 + yr) : (yq == 2) ? (4 + yr) : (3 - yr);
  int q0 = qt * 128, wq0 = wave * 32;

  const ushort* Qh = Qb + (size_t)bh * S_LEN * HD;
  const ushort* Kh = Kb + (size_t)bh * S_LEN * HD;
  const ushort* Vh = Vtb + (size_t)bh * HD * S_LEN;

  // ---- stage Q tile (swizzled) into Ks, pull B-frags into registers
#pragma unroll
  for (int cc = 0; cc < 4; ++cc) {
    int c = wave * 4 + cc;
    int s = c * 64 + lane;
    int row = s >> 3;
    int c8 = (s & 7) ^ (row & 7);
    gld_lds16(Qh + (size_t)(q0 + row) * HD + c8 * 8, &Ks[c * 512]);
  }
  __syncthreads();
  Frag qf[2][2];  // B-frag: B[d][qrow]
#pragma unroll
  for (int it = 0; it < 2; ++it)
#pragma unroll
    for (int ks = 0; ks < 2; ++ks) {
      int row = wq0 + it * 16 + l15;
      int c8 = (ks * 4 + quad) ^ (row & 7);
      qf[it][ks].q = *(const uint4*)&Ks[row * 64 + c8 * 8];
    }
  __syncthreads();  // qf readers done before kt=0 staging overwrites Ks

  Frag onesf;  // all-ones bf16 B-frag for the l-via-MFMA trick
  onesf.q = (uint4){0x3F803F80u, 0x3F803F80u, 0x3F803F80u, 0x3F803F80u};

  f32x4 lacc[2];
  f32x4 oacc[2][4];
#pragma unroll
  for (int it = 0; it < 2; ++it) {
    lacc[it] = (f32x4){0.f, 0.f, 0.f, 0.f};
#pragma unroll
    for (int dt = 0; dt < 4; ++dt) oacc[it][dt] = (f32x4){0.f, 0.f, 0.f, 0.f};
  }

  for (int kt = 0; kt <= qt; ++kt) {
    // ---- stage K (8 slots/row) and V^T (16 slots/row), both XOR-swizzled
#pragma unroll
    for (int cc = 0; cc < 4; ++cc) {
      int c = wave * 4 + cc;
      int s = c * 64 + lane;
      int krow = s >> 3, kc8 = (s & 7) ^ (krow & 7);
      int vrow = s >> 4, vc8 = (s & 15) ^ (vrow & 15);
      gld_lds16(Kh + (size_t)(kt * 128 + krow) * HD + kc8 * 8, &Ks[c * 512]);
      gld_lds16(Vh + (size_t)vrow * S_LEN + kt * 128 + vc8 * 8, &Vs[c * 512]);
    }
    __syncthreads();

    // ---- S^T = K · Q^T: pure MFMA burst (16 independent chains, pipelined)
    f32x4 sacc[2][8];
    __builtin_amdgcn_s_setprio(1);
#pragma unroll
    for (int jt = 0; jt < 8; ++jt) {
      int row = jt * 16 + l15;
      Frag kf0, kf1;
      kf0.q = *(const uint4*)&Ks[row * 64 + ((quad ^ (row & 7))) * 8];
      kf1.q = *(const uint4*)&Ks[row * 64 + (((4 + quad) ^ (row & 7))) * 8];
#pragma unroll
      for (int it = 0; it < 2; ++it) {
        f32x4 a = (f32x4){0.f, 0.f, 0.f, 0.f};
        a = mfma16(kf0, qf[it][0], a);
        a = mfma16(kf1, qf[it][1], a);
        sacc[it][jt] = a;
      }
    }
    __builtin_amdgcn_s_setprio(0);

    // ---- causal mask on the diagonal tile only
    if (kt == qt) {
#pragma unroll
      for (int it = 0; it < 2; ++it)
#pragma unroll
        for (int jt = 0; jt < 8; ++jt)
#pragma unroll
          for (int r = 0; r < 4; ++r)
            if (jt * 16 + quad * 4 + r > wq0 + it * 16 + l15)
              sacc[it][jt][r] = -1e30f;
    }

    // ---- exp2 + pack burst (no sum: l comes from the ones-MFMA below)
    uint sw[2][8][2];
#pragma unroll
    for (int it = 0; it < 2; ++it)
#pragma unroll
      for (int jt = 0; jt < 8; ++jt) {
        float p0 = exp2f(sacc[it][jt][0]);
        float p1 = exp2f(sacc[it][jt][1]);
        float p2 = exp2f(sacc[it][jt][2]);
        float p3 = exp2f(sacc[it][jt][3]);
        union { ushort2 h; uint u; } w0, w1;
        w0.h.x = f2bf_n(p0); w0.h.y = f2bf_n(p1);
        w1.h.x = f2bf_n(p2); w1.h.y = f2bf_n(p3);
        sw[it][jt][0] = w0.u;
        sw[it][jt][1] = w1.u;
      }

    // ---- in-register P redistribution: quads exchange at fixed l15.
    // x=[X0 X1 X2 X3] (by quad), y=[Y0..Y3]; after 32-swap: x'=[X0 X1 Y0 Y1],
    // y'=[X2 X3 Y2 Y3]; after 16-swap: x''=[X0 X2 Y0 Y2] (A-frag word u),
    // y''=[X1 X3 Y1 Y3] (A-frag word 2+u).
    Frag pf[2][4];
#pragma unroll
    for (int it = 0; it < 2; ++it)
#pragma unroll
      for (int ks = 0; ks < 4; ++ks) {
        uint x0 = sw[it][2 * ks][0], y0 = sw[it][2 * ks + 1][0];
        uint x1 = sw[it][2 * ks][1], y1 = sw[it][2 * ks + 1][1];
        asm("v_permlane32_swap_b32 %0, %1" : "+v"(x0), "+v"(y0));
        asm("v_permlane16_swap_b32 %0, %1" : "+v"(x0), "+v"(y0));
        asm("v_permlane32_swap_b32 %0, %1" : "+v"(x1), "+v"(y1));
        asm("v_permlane16_swap_b32 %0, %1" : "+v"(x1), "+v"(y1));
        pf[it][ks].q = (uint4){x0, x1, y0, y1};
      }

    // ---- O += P V  and  l += P · 1 (ones-MFMA; V frags shared across its)
    __builtin_amdgcn_s_setprio(1);
#pragma unroll
    for (int dt = 0; dt < 4; ++dt) {
      int row = dt * 16 + l15;
      Frag vf[4];
#pragma unroll
      for (int ks = 0; ks < 4; ++ks)
        vf[ks].q = *(const uint4*)&Vs[row * 128 + (((ks * 4 + quad) ^ (row & 15))) * 8];
#pragma unroll
      for (int it = 0; it < 2; ++it) {
        f32x4 a = oacc[it][dt];
#pragma unroll
        for (int ks = 0; ks < 4; ++ks) a = mfma16(pf[it][ks], vf[ks], a);
        oacc[it][dt] = a;
      }
    }
#pragma unroll
    for (int it = 0; it < 2; ++it) {
      f32x4 a = lacc[it];
#pragma unroll
      for (int ks = 0; ks < 4; ++ks) a = mfma16(pf[it][ks], onesf, a);
      lacc[it] = a;
    }
    __builtin_amdgcn_s_setprio(0);

    __syncthreads();  // all waves done with Ks/Vs before restage
  }

  // ---- epilogue: normalize by l (lacc[it][r] = l[q], uniform over l15)
  int b = bh >> 4, h = bh & 15;
#pragma unroll
  for (int it = 0; it < 2; ++it) {
    float lr[4];
#pragma unroll
    for (int r = 0; r < 4; ++r) lr[r] = 1.f / lacc[it][r];
#pragma unroll
    for (int r = 0; r < 4; ++r) {
      int qg = q0 + wq0 + it * 16 + quad * 4 + r;
      size_t base = ((size_t)(b * S_LEN + qg)) * DIM + h * HD;
#pragma unroll
      for (int dt = 0; dt < 4; ++dt)
        Ctx[base + dt * 16 + l15] = f2bf_n(oacc[it][dt][r] * lr[r]);
    }
  }
}

// ---------------- launch ----------------
extern "C" void kernel_launch(void* const* d_in, const int* in_sizes, int n_in,
                              void* d_out, int out_size, void* d_ws, size_t ws_size,
                              hipStream_t stream) {
  (void)in_sizes; (void)n_in; (void)out_size; (void)ws_size;
  const float* x  = (const float*)d_in[0];
  const float* Wq = (const float*)d_in[1];
  const float* Wk = (const float*)d_in[2];
  const float* Wv = (const float*)d_in[3];
  const float* Wo = (const float*)d_in[4];
  const float* bo = (const float*)d_in[5];
  float* out = (float*)d_out;

  ushort* Xb  = (ushort*)d_ws;                     // [8192][1024]
  ushort* Wqb = Xb  + (size_t)M_ROWS * DIM;
  ushort* Wkb = Wqb + (size_t)DIM * DIM;
  ushort* Wvb = Wkb + (size_t)DIM * DIM;
  ushort* Wob = Wvb + (size_t)DIM * DIM;
  ushort* Qb  = Wob + (size_t)DIM * DIM;           // [B,H,S,HD] (pre-scaled)
  ushort* Kb  = Qb  + (size_t)M_ROWS * DIM;        // [B,H,S,HD]
  ushort* Vtb = Kb  + (size_t)M_ROWS * DIM;        // [B,H,HD,S]
  ushort* Ctx = Vtb + (size_t)M_ROWS * DIM;        // [B,S,D]

  const float SCALE_Q = 0.18033688011112042f;  // log2(e) / sqrt(HD)

  cast_x_kernel<<<dim3(M_ROWS * DIM / 1024), 256, 0, stream>>>(x, Xb);
  cast_w_kernel<<<dim3(DIM * DIM / 1024, 4), 256, 0, stream>>>(Wq, Wk, Wv, Wo, Wqb, Wkb, Wvb, Wob);

  gemm_bk64<0><<<dim3(24, 64), 256, 0, stream>>>(Xb, Wqb, Wkb, Wvb, Qb, Kb, Vtb,
                                                 nullptr, nullptr, SCALE_Q);

  flash_attn<<<dim3(BATCH * NH, S_LEN / 128), 256, 0, stream>>>(Qb, Kb, Vtb, Ctx);

  gemm_bk64<1><<<dim3(8, 64), 256, 0, stream>>>(Ctx, Wob, nullptr, nullptr, nullptr, nullptr,
                                                nullptr, out, bo, 1.0f);
}